// Round 1
// 832.715 us; speedup vs baseline: 1.2794x; 1.2794x over previous
//
#include <hip/hip_runtime.h>
#include <hip/hip_bf16.h>

typedef __bf16 bf16;
typedef __bf16 bf16x4 __attribute__((ext_vector_type(4)));
typedef __bf16 bf16x8 __attribute__((ext_vector_type(8)));
typedef float f32x4 __attribute__((ext_vector_type(4)));

#define GLD16(gp, sp) __builtin_amdgcn_global_load_lds( \
    (const __attribute__((address_space(1))) void*)(gp), \
    (__attribute__((address_space(3))) void*)(sp), 16, 0, 0)

#define FENCE() asm volatile("" ::: "memory")
#define BARRIER() do { FENCE(); __builtin_amdgcn_s_barrier(); FENCE(); } while (0)

constexpr int UNITS = 8;
constexpr int BATCH = 65536;
constexpr int DIM   = 256;          // I == H == 256
constexpr int BM    = 256;          // rows per block (persistent m-tile)
constexpr int BN    = 32;           // j-tile columns
constexpr int BK    = 32;           // K-chunk
constexpr int KC    = DIM / BK;     // 8
constexpr int JT    = DIM / BN;     // 8
constexpr size_t WN = (size_t)UNITS * 3 * DIM * DIM;  // 1,572,864 per weight tensor

__device__ __forceinline__ float sigmoidf_fast(float x) {
    return 1.0f / (1.0f + __expf(-x));
}
__device__ __forceinline__ float tanhf_fast(float x) {
    float y = fminf(fmaxf(x, -15.0f), 15.0f);
    float e = __expf(-2.0f * y);
    return (1.0f - e) / (1.0f + e);
}
// byte offset into the swizzled h tile: XOR row bits into the 16B-slot bits
// (row stride 512B == 0 mod 128B banks -> without this, ds_read_b128 is 16-way)
__device__ __forceinline__ unsigned hsoff(int row, int col) {
    return (unsigned)((row * DIM + col) * 2) ^ (unsigned)((row & 7) << 4);
}
__device__ __forceinline__ float bfbits2f(unsigned b) {
    return __builtin_bit_cast(float, b << 16);
}
__device__ __forceinline__ unsigned f2bfbits(float f) {
    return (unsigned)__builtin_bit_cast(unsigned short, (bf16)f);
}

// ---------------------------------------------------------------------------
// f32 -> bf16 weights, plus combined gate biases:
// bcomb[u][0..256)=bih_r+bhh_r, [256..512)=bih_z+bhh_z, [512..768)=bih_n, [768..1024)=bhh_n
__global__ void convert_kernel(const float* __restrict__ Wih,
                               const float* __restrict__ Whh,
                               const float* __restrict__ bih,
                               const float* __restrict__ bhh,
                               bf16* __restrict__ Wihbf,
                               bf16* __restrict__ Whhbf,
                               float* __restrict__ bcomb)
{
    const size_t W4 = 2 * WN / 4;   // 786432 float4 conversions
    size_t i = (size_t)blockIdx.x * blockDim.x + threadIdx.x;
    if (i < W4) {
        size_t e = i * 4;
        const float* src = (e < WN) ? Wih : Whh;
        bf16* dst        = (e < WN) ? Wihbf : Whhbf;
        size_t off       = (e < WN) ? e : e - WN;
        const float4 v = *(const float4*)(src + off);
        bf16x4 o;
        o[0] = (bf16)v.x; o[1] = (bf16)v.y; o[2] = (bf16)v.z; o[3] = (bf16)v.w;
        *(bf16x4*)(dst + off) = o;
    } else {
        size_t j = i - W4;          // 0..8191
        if (j < (size_t)UNITS * 1024) {
            int u = (int)(j >> 10), t = (int)(j & 1023);
            const float* bi = bih + u * 768;
            const float* bh = bhh + u * 768;
            float v;
            if (t < 512)      v = bi[t] + bh[t];   // r, z merged biases
            else if (t < 768) v = bi[t];           // bni
            else              v = bh[t - 256];     // bnh
            bcomb[u * 1024 + t] = v;
        }
    }
}

// ---------------------------------------------------------------------------
// stage the (u,jt,kc) weight subtiles (wi: 3x32 j-rows x 32 k, wh: same) into wb.
// Global source column is pre-swizzled ( (lane&3)^(srow&3) ) so that the
// linear global_load_lds destination yields the bank-conflict-free read layout.
__device__ __forceinline__ void stage_w(const bf16* __restrict__ Wihbf,
                                        const bf16* __restrict__ Whhbf,
                                        bf16* wb, int sg, int wave, int lane)
{
    const int u  = sg >> 6;
    const int jt = (sg >> 3) & 7;
    const int kc = sg & 7;
    const bf16* Wi = Wihbf + (size_t)u * (3 * DIM * DIM);
    const bf16* Wh = Whhbf + (size_t)u * (3 * DIM * DIM);
    const int srow = lane >> 2;                         // 0..15
    const int scol = ((lane & 3) ^ (srow & 3)) << 3;    // pre-swizzled source col
    const int j0 = jt * BN, k0 = kc * BK;
    {   // chunks 0..7: waves 0-5 -> wi chunk, waves 6-7 -> wh chunks 0,1
        const int cc = (wave < 6) ? wave : wave - 6;
        const bf16* W = (wave < 6) ? Wi : Wh;
        bf16* d = wb + ((wave < 6) ? 0 : 3 * BN * BK) + cc * 512;
        const int grow = (cc >> 1) * DIM + j0 + ((cc & 1) << 4) + srow;
        GLD16(W + (size_t)grow * DIM + k0 + scol, d);
    }
    if (wave < 4) {   // chunks 8..11 -> wh chunks 2..5
        const int cc = wave + 2;
        const int grow = (cc >> 1) * DIM + j0 + ((cc & 1) << 4) + srow;
        GLD16(Wh + (size_t)grow * DIM + k0 + scol, wb + 3 * BN * BK + cc * 512);
    }
}

// ---------------------------------------------------------------------------
// Fused 8-unit GRU chain. One block = one 256-row batch tile, persistent
// across all units. h lives in LDS (bf16, swizzled); x lives in VGPR A-frags;
// weights double-buffer-stream through 24KB of LDS.
__global__ __launch_bounds__(512, 2)
void gru_fused_kernel(const float* __restrict__ xg,     // [B,256] f32
                      const float* __restrict__ h0g,    // [256] f32
                      const bf16* __restrict__ Wihbf,   // [8,768,256] bf16
                      const bf16* __restrict__ Whhbf,   // [8,768,256] bf16
                      const float* __restrict__ bcomb,  // [8,1024] f32
                      float* __restrict__ out)          // [B,256] f32
{
    __shared__ __align__(16) bf16 hs[BM * DIM];                // 128 KB
    __shared__ __align__(16) bf16 wbuf[2][2 * 3 * BN * BK];    // 24 KB
    __shared__ float bias_lds[4 * DIM];                        // 4 KB  => 156 KB

    const int tid  = threadIdx.x;
    const int wave = tid >> 6;
    const int lane = tid & 63;
    const int quad = lane >> 4;
    const int l15  = lane & 15;
    const int odd  = l15 & 1;
    const int m0   = blockIdx.x * BM;

    // ---- x m-tile -> persistent A-fragments (f32 load, bf16 convert) ----
    bf16x8 xf[2][KC];
#pragma unroll
    for (int mt = 0; mt < 2; ++mt) {
        const int row = m0 + wave * 32 + mt * 16 + l15;
        const float* xr = xg + (size_t)row * DIM + quad * 8;
#pragma unroll
        for (int kc = 0; kc < KC; ++kc) {
            const float4 a = *(const float4*)(xr + kc * 32);
            const float4 b = *(const float4*)(xr + kc * 32 + 4);
            bf16x8 v;
            v[0]=(bf16)a.x; v[1]=(bf16)a.y; v[2]=(bf16)a.z; v[3]=(bf16)a.w;
            v[4]=(bf16)b.x; v[5]=(bf16)b.y; v[6]=(bf16)b.z; v[7]=(bf16)b.w;
            xf[mt][kc] = v;
        }
    }

    // ---- h0 broadcast fill of hs (swizzled) ----
    {
        const int c8 = (tid & 31) * 8;
        const int r0 = tid >> 5;
        const float4 a = *(const float4*)(h0g + c8);
        const float4 b = *(const float4*)(h0g + c8 + 4);
        bf16x8 v;
        v[0]=(bf16)a.x; v[1]=(bf16)a.y; v[2]=(bf16)a.z; v[3]=(bf16)a.w;
        v[4]=(bf16)b.x; v[5]=(bf16)b.y; v[6]=(bf16)b.z; v[7]=(bf16)b.w;
#pragma unroll
        for (int i = 0; i < 16; ++i)
            *(bf16x8*)((char*)hs + hsoff(r0 + i * 16, c8)) = v;
    }
    // bias for unit 0 + first weight stage
    bias_lds[tid]       = bcomb[tid];
    bias_lds[tid + 512] = bcomb[tid + 512];
    stage_w(Wihbf, Whhbf, wbuf[0], 0, wave, lane);
    __syncthreads();

    unsigned hn[JT][2][2][2];   // packed h_new (2 cols x 2 rows per reg), 64 VGPRs

    for (int u = 0; u < UNITS; ++u) {
        if (u) {   // reload biases for this unit (full fences via syncthreads)
            __syncthreads();
            const float* bc = bcomb + u * 1024;
            bias_lds[tid]       = bc[tid];
            bias_lds[tid + 512] = bc[tid + 512];
            __syncthreads();
        }
#pragma unroll
        for (int jt = 0; jt < JT; ++jt) {
            // acc groups: 0=r (merged), 1=z (merged), 2=n_i, 3=n_h.
            // biases folded into the accumulator init.
            f32x4 acc[4][2][2];
#pragma unroll
            for (int tn = 0; tn < 2; ++tn) {
                const int j = jt * BN + tn * 16 + l15;
                const float br  = bias_lds[j];
                const float bz  = bias_lds[DIM + j];
                const float bni = bias_lds[2 * DIM + j];
                const float bnh = bias_lds[3 * DIM + j];
#pragma unroll
                for (int mt = 0; mt < 2; ++mt) {
                    acc[0][mt][tn] = (f32x4){br, br, br, br};
                    acc[1][mt][tn] = (f32x4){bz, bz, bz, bz};
                    acc[2][mt][tn] = (f32x4){bni, bni, bni, bni};
                    acc[3][mt][tn] = (f32x4){bnh, bnh, bnh, bnh};
                }
            }
#pragma unroll
            for (int kc = 0; kc < KC; ++kc) {
                // s = current step; buf[s&1] holds this step's weights.
                // drain my stage(s) (issued one body ago -> latency hidden):
                asm volatile("s_waitcnt vmcnt(0)" ::: "memory");
                BARRIER();   // A: all waves done reading buf[(s+1)&1]
                if (!(jt == JT - 1 && kc == KC - 1) || u < UNITS - 1)
                    stage_w(Wihbf, Whhbf, wbuf[(jt * 8 + kc + 1) & 1],
                            u * 64 + jt * 8 + kc + 1, wave, lane);
                BARRIER();   // B: everyone's stage(s) landed (each drained pre-A)
                const bf16* wt = wbuf[(jt * 8 + kc) & 1];
                const bf16* wi = wt;
                const bf16* wh = wt + 3 * BN * BK;
                const int kq = (quad ^ (l15 & 3)) << 3;   // swizzled k-offset
                bf16x8 ah[2];
#pragma unroll
                for (int mt = 0; mt < 2; ++mt)
                    ah[mt] = *(const bf16x8*)((const char*)hs +
                               hsoff(wave * 32 + mt * 16 + l15, kc * 32 + quad * 8));
#pragma unroll
                for (int g = 0; g < 3; ++g) {
                    const int r0 = g * BN + l15;
                    const int r1 = r0 + 16;
                    const bf16x8 bi0 = *(const bf16x8*)(wi + r0 * BK + kq);
                    const bf16x8 bi1 = *(const bf16x8*)(wi + r1 * BK + kq);
                    const bf16x8 bh0 = *(const bf16x8*)(wh + r0 * BK + kq);
                    const bf16x8 bh1 = *(const bf16x8*)(wh + r1 * BK + kq);
                    if (g < 2) {
#pragma unroll
                        for (int mt = 0; mt < 2; ++mt) {
                            acc[g][mt][0] = __builtin_amdgcn_mfma_f32_16x16x32_bf16(xf[mt][kc], bi0, acc[g][mt][0], 0, 0, 0);
                            acc[g][mt][1] = __builtin_amdgcn_mfma_f32_16x16x32_bf16(xf[mt][kc], bi1, acc[g][mt][1], 0, 0, 0);
                            acc[g][mt][0] = __builtin_amdgcn_mfma_f32_16x16x32_bf16(ah[mt], bh0, acc[g][mt][0], 0, 0, 0);
                            acc[g][mt][1] = __builtin_amdgcn_mfma_f32_16x16x32_bf16(ah[mt], bh1, acc[g][mt][1], 0, 0, 0);
                        }
                    } else {
#pragma unroll
                        for (int mt = 0; mt < 2; ++mt) {
                            acc[2][mt][0] = __builtin_amdgcn_mfma_f32_16x16x32_bf16(xf[mt][kc], bi0, acc[2][mt][0], 0, 0, 0);
                            acc[2][mt][1] = __builtin_amdgcn_mfma_f32_16x16x32_bf16(xf[mt][kc], bi1, acc[2][mt][1], 0, 0, 0);
                            acc[3][mt][0] = __builtin_amdgcn_mfma_f32_16x16x32_bf16(ah[mt], bh0, acc[3][mt][0], 0, 0, 0);
                            acc[3][mt][1] = __builtin_amdgcn_mfma_f32_16x16x32_bf16(ah[mt], bh1, acc[3][mt][1], 0, 0, 0);
                        }
                    }
                }
            }
            // ---- epilogue: activations for this j-tile -> packed hn regs ----
            // C/D layout: col = l15 (per tn), row = quad*4 + i.
            // Even/odd lane pairs exchange halves so h_prev reads and h_new
            // writes are full-dword LDS ops (2 adjacent cols per b32).
#pragma unroll
            for (int mt = 0; mt < 2; ++mt) {
#pragma unroll
                for (int tn = 0; tn < 2; ++tn) {
                    const int rbase = wave * 32 + mt * 16 + quad * 4;
                    const int rowA  = rbase + 2 * odd;
                    const int colb  = jt * 32 + tn * 16 + (l15 & ~1);
                    const unsigned d0 = *(const unsigned*)((const char*)hs + hsoff(rowA,     colb));
                    const unsigned d1 = *(const unsigned*)((const char*)hs + hsoff(rowA + 1, colb));
                    const unsigned o0 = (unsigned)__shfl_xor((int)d0, 1);
                    const unsigned o1 = (unsigned)__shfl_xor((int)d1, 1);
                    const unsigned p0 = odd ? o0 : d0;   // row rbase+0 col-pair
                    const unsigned p1 = odd ? o1 : d1;   // row rbase+1
                    const unsigned p2 = odd ? d0 : o0;   // row rbase+2
                    const unsigned p3 = odd ? d1 : o1;   // row rbase+3
                    const int sh = odd ? 16 : 0;
                    float hp[4];
                    hp[0] = bfbits2f((p0 >> sh) & 0xffffu);
                    hp[1] = bfbits2f((p1 >> sh) & 0xffffu);
                    hp[2] = bfbits2f((p2 >> sh) & 0xffffu);
                    hp[3] = bfbits2f((p3 >> sh) & 0xffffu);
                    unsigned bb[4];
#pragma unroll
                    for (int i = 0; i < 4; ++i) {
                        const float r_ = sigmoidf_fast(acc[0][mt][tn][i]);
                        const float z_ = sigmoidf_fast(acc[1][mt][tn][i]);
                        const float n_ = tanhf_fast(acc[2][mt][tn][i] + r_ * acc[3][mt][tn][i]);
                        const float hv = fmaf(z_, hp[i] - n_, n_);
                        bb[i] = f2bfbits(hv);
                    }
                    const unsigned lo  = bb[0] | (bb[1] << 16);
                    const unsigned hi  = bb[2] | (bb[3] << 16);
                    const unsigned olo = (unsigned)__shfl_xor((int)lo, 1);
                    const unsigned ohi = (unsigned)__shfl_xor((int)hi, 1);
                    unsigned w0, w1;
                    if (odd) {   // rows rbase+2, rbase+3
                        w0 = (ohi & 0xffffu) | (hi << 16);
                        w1 = (ohi >> 16)     | (hi & 0xffff0000u);
                    } else {     // rows rbase+0, rbase+1
                        w0 = (lo & 0xffffu)  | (olo << 16);
                        w1 = (lo >> 16)      | (olo & 0xffff0000u);
                    }
                    hn[jt][mt][tn][0] = w0;
                    hn[jt][mt][tn][1] = w1;
                }
            }
        }
        // ---- commit h_new -> hs. Rows are wave-private: no barrier needed. ----
#pragma unroll
        for (int jt = 0; jt < JT; ++jt)
#pragma unroll
            for (int mt = 0; mt < 2; ++mt)
#pragma unroll
                for (int tn = 0; tn < 2; ++tn) {
                    const int rowA = wave * 32 + mt * 16 + quad * 4 + 2 * odd;
                    const int colb = jt * 32 + tn * 16 + (l15 & ~1);
                    *(unsigned*)((char*)hs + hsoff(rowA,     colb)) = hn[jt][mt][tn][0];
                    *(unsigned*)((char*)hs + hsoff(rowA + 1, colb)) = hn[jt][mt][tn][1];
                }
    }

    // ---- coalesced f32 flush of the final h ----
    __syncthreads();
    {
        const int c8 = (tid & 31) * 8;
        const int r0 = tid >> 5;
#pragma unroll
        for (int i = 0; i < 16; ++i) {
            const int r = r0 + i * 16;
            const bf16x8 v = *(const bf16x8*)((const char*)hs + hsoff(r, c8));
            float4 a, b;
            a.x = (float)v[0]; a.y = (float)v[1]; a.z = (float)v[2]; a.w = (float)v[3];
            b.x = (float)v[4]; b.y = (float)v[5]; b.z = (float)v[6]; b.w = (float)v[7];
            float* o = out + (size_t)(m0 + r) * DIM + c8;
            *(float4*)o       = a;
            *(float4*)(o + 4) = b;
        }
    }
}

// ---------------------------------------------------------------------------
extern "C" void kernel_launch(void* const* d_in, const int* in_sizes, int n_in,
                              void* d_out, int out_size, void* d_ws, size_t ws_size,
                              hipStream_t stream) {
    const float* x   = (const float*)d_in[0];
    const float* Wih = (const float*)d_in[1];   // [8,768,256] f32
    const float* Whh = (const float*)d_in[2];   // [8,768,256] f32
    const float* bih = (const float*)d_in[3];   // [8,768] f32
    const float* bhh = (const float*)d_in[4];   // [8,768] f32
    const float* h0  = (const float*)d_in[5];   // [256] f32
    float* out = (float*)d_out;                 // [B,256] f32

    // ws layout: Wihbf[WN] | Whhbf[WN] (bf16) | bcomb[8*1024] (f32)  ~6.3 MB
    bf16* Wihbf  = (bf16*)d_ws;
    bf16* Whhbf  = Wihbf + WN;
    float* bcomb = (float*)(Whhbf + WN);

    {
        const size_t total = 2 * WN / 4 + (size_t)UNITS * 1024;   // 794,624
        const int cblocks = (int)((total + 255) / 256);
        hipLaunchKernelGGL(convert_kernel, dim3(cblocks), dim3(256), 0, stream,
                           Wih, Whh, bih, bhh, Wihbf, Whhbf, bcomb);
    }
    hipLaunchKernelGGL(gru_fused_kernel, dim3(BATCH / BM), dim3(512), 0, stream,
                       x, h0, Wihbf, Whhbf, bcomb, out);
}

// Round 2
// 708.912 us; speedup vs baseline: 1.5029x; 1.1746x over previous
//
#include <hip/hip_runtime.h>
#include <hip/hip_bf16.h>

typedef __bf16 bf16;
typedef __bf16 bf16x4 __attribute__((ext_vector_type(4)));
typedef __bf16 bf16x8 __attribute__((ext_vector_type(8)));
typedef float f32x4 __attribute__((ext_vector_type(4)));

#define GLD16(gp, sp) __builtin_amdgcn_global_load_lds( \
    (const __attribute__((address_space(1))) void*)(gp), \
    (__attribute__((address_space(3))) void*)(sp), 16, 0, 0)

#define FENCE() asm volatile("" ::: "memory")
#define BARRIER() do { FENCE(); __builtin_amdgcn_s_barrier(); FENCE(); } while (0)

constexpr int UNITS = 8;
constexpr int BATCH = 65536;
constexpr int DIM   = 256;          // I == H == 256
constexpr int BM    = 256;          // rows per block (persistent m-tile)
constexpr int BN    = 16;           // j-tile columns
constexpr int BK    = 64;           // K per staged buffer (2 MFMA k-steps)
constexpr int JT    = DIM / BN;     // 16 j-tiles
constexpr int STEPS_PER_UNIT = JT * 4;          // 64 (4 k-pairs per jt)
constexpr int TOT_STEPS = UNITS * STEPS_PER_UNIT;   // 512
constexpr int WTILE = 3 * BN * BK;  // 3072 bf16 elems = 6 KB (wi or wh)
constexpr size_t WN = (size_t)UNITS * 3 * DIM * DIM;  // 1,572,864 per weight tensor

__device__ __forceinline__ float sigmoidf_fast(float x) {
    return 1.0f / (1.0f + __expf(-x));
}
__device__ __forceinline__ float tanhf_fast(float x) {
    float y = fminf(fmaxf(x, -15.0f), 15.0f);
    float e = __expf(-2.0f * y);
    return (1.0f - e) / (1.0f + e);
}
// byte offset into the swizzled h tile (512B rows): XOR row bits into the
// 16B-slot bits; without it every 16-lane column read is a 16-way conflict.
__device__ __forceinline__ unsigned hsoff(int row, int col) {
    return (unsigned)((row * DIM + col) * 2) ^ (unsigned)((row & 7) << 4);
}
__device__ __forceinline__ float bfbits2f(unsigned b) {
    return __builtin_bit_cast(float, b << 16);
}
__device__ __forceinline__ unsigned f2bfbits(float f) {
    return (unsigned)__builtin_bit_cast(unsigned short, (bf16)f);
}

// ---------------------------------------------------------------------------
// f32 -> bf16 weights, plus combined gate biases:
// bcomb[u][0..256)=bih_r+bhh_r, [256..512)=bih_z+bhh_z, [512..768)=bih_n, [768..1024)=bhh_n
__global__ void convert_kernel(const float* __restrict__ Wih,
                               const float* __restrict__ Whh,
                               const float* __restrict__ bih,
                               const float* __restrict__ bhh,
                               bf16* __restrict__ Wihbf,
                               bf16* __restrict__ Whhbf,
                               float* __restrict__ bcomb)
{
    const size_t W4 = 2 * WN / 4;   // 786432 float4 conversions
    size_t i = (size_t)blockIdx.x * blockDim.x + threadIdx.x;
    if (i < W4) {
        size_t e = i * 4;
        const float* src = (e < WN) ? Wih : Whh;
        bf16* dst        = (e < WN) ? Wihbf : Whhbf;
        size_t off       = (e < WN) ? e : e - WN;
        const float4 v = *(const float4*)(src + off);
        bf16x4 o;
        o[0] = (bf16)v.x; o[1] = (bf16)v.y; o[2] = (bf16)v.z; o[3] = (bf16)v.w;
        *(bf16x4*)(dst + off) = o;
    } else {
        size_t j = i - W4;          // 0..8191
        if (j < (size_t)UNITS * 1024) {
            int u = (int)(j >> 10), t = (int)(j & 1023);
            const float* bi = bih + u * 768;
            const float* bh = bhh + u * 768;
            float v;
            if (t < 512)      v = bi[t] + bh[t];   // r, z merged biases
            else if (t < 768) v = bi[t];           // bni
            else              v = bh[t - 256];     // bnh
            bcomb[u * 1024 + t] = v;
        }
    }
}

// ---------------------------------------------------------------------------
// Stage the (u,jt,pair) weight buffer: wi = 48 rows (3 gates x 16 j-cols) x
// 64 k, wh same -> 12 x 1KB chunks (8 rows x 128B each).
// Weight rows are 128B, so the conflict-free read key is the FULL (row&7);
// the global source k-chunk is pre-swizzled so the linear global_load_lds
// destination yields the swizzled layout (both-sides-or-neither rule).
__device__ __forceinline__ void stage_w(const bf16* __restrict__ Wihbf,
                                        const bf16* __restrict__ Whhbf,
                                        bf16* wb, int sg, int wave, int lane)
{
    const int u    = sg >> 6;
    const int jt   = (sg >> 2) & 15;
    const int pair = sg & 3;
    const int k0   = pair * 64;
    const bf16* Wi = Wihbf + (size_t)u * (3 * DIM * DIM);
    const bf16* Wh = Whhbf + (size_t)u * (3 * DIM * DIM);
    const int rr   = lane >> 3;                     // row-in-chunk 0..7
    const int scol = ((lane & 7) ^ rr) << 3;        // pre-swizzled k elems
    {   // chunk c = wave: c<6 -> wi chunk c, else wh chunk c-6
        const int c  = wave;
        const bf16* W = (c < 6) ? Wi : Wh;
        const int cc = (c < 6) ? c : c - 6;
        bf16* d = wb + ((c < 6) ? 0 : WTILE) + cc * 512;
        const int r = cc * 8 + rr;                  // tile row 0..47
        const int grow = (r >> 4) * DIM + jt * BN + (r & 15);
        GLD16(W + (size_t)grow * DIM + k0 + scol, d);
    }
    if (wave < 4) {   // chunks 8..11 -> wh chunks 2..5
        const int cc = wave + 2;
        const int r = cc * 8 + rr;
        const int grow = (r >> 4) * DIM + jt * BN + (r & 15);
        GLD16(Wh + (size_t)grow * DIM + k0 + scol, wb + WTILE + cc * 512);
    }
}

// ---------------------------------------------------------------------------
// Fused 8-unit GRU chain. One block = 256 batch rows, persistent.
// x AND h_prev live in VGPR A-fragments (h rows never cross waves); hs (LDS)
// is only the C-layout home of h for the epilogue + once-per-unit A-relayout.
// Weights double-buffer-stream through 2 x 12KB with ONE barrier per step.
__global__ __launch_bounds__(512, 2)
void gru_fused_kernel(const float* __restrict__ xg,     // [B,256] f32
                      const float* __restrict__ h0g,    // [256] f32
                      const bf16* __restrict__ Wihbf,   // [8,768,256] bf16
                      const bf16* __restrict__ Whhbf,   // [8,768,256] bf16
                      const float* __restrict__ bcomb,  // [8,1024] f32
                      float* __restrict__ out)          // [B,256] f32
{
    __shared__ __align__(16) bf16 hs[BM * DIM];       // 128 KB
    __shared__ __align__(16) bf16 wbuf[2][2 * WTILE]; // 24 KB => 152 KB total

    const int tid  = threadIdx.x;
    const int wave = tid >> 6;
    const int lane = tid & 63;
    const int quad = lane >> 4;
    const int l15  = lane & 15;
    const int odd  = l15 & 1;
    const int m0   = blockIdx.x * BM;

    // ---- x m-tile -> persistent A-fragments (f32 load, bf16 convert) ----
    bf16x8 xf[2][8];
#pragma unroll
    for (int mt = 0; mt < 2; ++mt) {
        const int row = m0 + wave * 32 + mt * 16 + l15;
        const float* xr = xg + (size_t)row * DIM + quad * 8;
#pragma unroll
        for (int kc = 0; kc < 8; ++kc) {
            const float4 a = *(const float4*)(xr + kc * 32);
            const float4 b = *(const float4*)(xr + kc * 32 + 4);
            bf16x8 v;
            v[0]=(bf16)a.x; v[1]=(bf16)a.y; v[2]=(bf16)a.z; v[3]=(bf16)a.w;
            v[4]=(bf16)b.x; v[5]=(bf16)b.y; v[6]=(bf16)b.z; v[7]=(bf16)b.w;
            xf[mt][kc] = v;
        }
    }

    // ---- h0 -> hf A-fragments (broadcast: same cols for every row) ----
    bf16x8 hf[2][8];
#pragma unroll
    for (int kc = 0; kc < 8; ++kc) {
        const float4 a = *(const float4*)(h0g + kc * 32 + quad * 8);
        const float4 b = *(const float4*)(h0g + kc * 32 + quad * 8 + 4);
        bf16x8 v;
        v[0]=(bf16)a.x; v[1]=(bf16)a.y; v[2]=(bf16)a.z; v[3]=(bf16)a.w;
        v[4]=(bf16)b.x; v[5]=(bf16)b.y; v[6]=(bf16)b.z; v[7]=(bf16)b.w;
        hf[0][kc] = v;
        hf[1][kc] = v;
    }
    // ---- hs := h0 (own rows; epilogue of unit 0 reads h_prev from here) ----
#pragma unroll
    for (int mt = 0; mt < 2; ++mt)
#pragma unroll
        for (int kc = 0; kc < 8; ++kc)
            *(bf16x8*)((char*)hs + hsoff(wave * 32 + mt * 16 + l15,
                                         kc * 32 + quad * 8)) = hf[mt][kc];

    stage_w(Wihbf, Whhbf, (bf16*)wbuf[0], 0, wave, lane);   // prologue stage

    for (int u = 0; u < UNITS; ++u) {
        const float* bc = bcomb + u * 1024;
        for (int jt = 0; jt < JT; ++jt) {
            // bias loads issued at jt top; latency hidden under the k loop
            const int jc = jt * BN + l15;
            const float br  = bc[jc];
            const float bz  = bc[DIM + jc];
            const float bni = bc[2 * DIM + jc];
            const float bnh = bc[3 * DIM + jc];

            f32x4 acc[4][2];   // [r, z, n_i, n_h][mt]
#pragma unroll
            for (int g = 0; g < 4; ++g)
#pragma unroll
                for (int mt = 0; mt < 2; ++mt)
                    acc[g][mt] = (f32x4){0.f, 0.f, 0.f, 0.f};

            const int sg0 = u * STEPS_PER_UNIT + jt * 4;
#pragma unroll
            for (int pair = 0; pair < 4; ++pair) {
                const int sg = sg0 + pair;
                // drain MY stage chunks (issued one body ago), then rendezvous.
                // One barrier suffices: every wave drained its own vmcnt
                // before arriving, and the buffer being re-staged was freed
                // by this same barrier.
                asm volatile("s_waitcnt vmcnt(0)" ::: "memory");
                BARRIER();
                if (sg + 1 < TOT_STEPS)
                    stage_w(Wihbf, Whhbf, (bf16*)wbuf[(sg + 1) & 1],
                            sg + 1, wave, lane);
                const bf16* wt = wbuf[sg & 1];
#pragma unroll
                for (int kc2 = 0; kc2 < 2; ++kc2) {
                    const int kcg = pair * 2 + kc2;
                    bf16x8 bi[3], bh[3];
#pragma unroll
                    for (int g = 0; g < 3; ++g) {
                        // 128B rows, slot = (kc2*4+quad) ^ (row&7): 2-way = free
                        const int off = (g * BN + l15) * BK
                                      + (((kc2 * 4 + quad) ^ (l15 & 7)) << 3);
                        bi[g] = *(const bf16x8*)(wt + off);
                        bh[g] = *(const bf16x8*)(wt + WTILE + off);
                    }
#pragma unroll
                    for (int mt = 0; mt < 2; ++mt) {
                        acc[0][mt] = __builtin_amdgcn_mfma_f32_16x16x32_bf16(xf[mt][kcg], bi[0], acc[0][mt], 0, 0, 0);
                        acc[0][mt] = __builtin_amdgcn_mfma_f32_16x16x32_bf16(hf[mt][kcg], bh[0], acc[0][mt], 0, 0, 0);
                        acc[1][mt] = __builtin_amdgcn_mfma_f32_16x16x32_bf16(xf[mt][kcg], bi[1], acc[1][mt], 0, 0, 0);
                        acc[1][mt] = __builtin_amdgcn_mfma_f32_16x16x32_bf16(hf[mt][kcg], bh[1], acc[1][mt], 0, 0, 0);
                        acc[2][mt] = __builtin_amdgcn_mfma_f32_16x16x32_bf16(xf[mt][kcg], bi[2], acc[2][mt], 0, 0, 0);
                        acc[3][mt] = __builtin_amdgcn_mfma_f32_16x16x32_bf16(hf[mt][kcg], bh[2], acc[3][mt], 0, 0, 0);
                    }
                }
            }

            // ---- epilogue: activations, write h_new through to hs ----
            // hf regs still hold full h_prev, so writing hs per-jt is safe.
            // C/D layout: col = l15, row = quad*4 + i. Even/odd lane pairs
            // exchange halves so hs reads/writes are full-dword ops.
#pragma unroll
            for (int mt = 0; mt < 2; ++mt) {
                const int rbase = wave * 32 + mt * 16 + quad * 4;
                const int rowA  = rbase + 2 * odd;
                const int colb  = jt * BN + (l15 & ~1);
                const unsigned d0 = *(const unsigned*)((const char*)hs + hsoff(rowA,     colb));
                const unsigned d1 = *(const unsigned*)((const char*)hs + hsoff(rowA + 1, colb));
                const unsigned o0 = (unsigned)__shfl_xor((int)d0, 1);
                const unsigned o1 = (unsigned)__shfl_xor((int)d1, 1);
                const unsigned p0 = odd ? o0 : d0;   // row rbase+0 col-pair
                const unsigned p1 = odd ? o1 : d1;   // row rbase+1
                const unsigned p2 = odd ? d0 : o0;   // row rbase+2
                const unsigned p3 = odd ? d1 : o1;   // row rbase+3
                const int sh = odd ? 16 : 0;
                float hp[4];
                hp[0] = bfbits2f((p0 >> sh) & 0xffffu);
                hp[1] = bfbits2f((p1 >> sh) & 0xffffu);
                hp[2] = bfbits2f((p2 >> sh) & 0xffffu);
                hp[3] = bfbits2f((p3 >> sh) & 0xffffu);
                unsigned bb[4];
#pragma unroll
                for (int i = 0; i < 4; ++i) {
                    const float r_ = sigmoidf_fast(acc[0][mt][i] + br);
                    const float z_ = sigmoidf_fast(acc[1][mt][i] + bz);
                    const float n_ = tanhf_fast(acc[2][mt][i] + bni
                                                + r_ * (acc[3][mt][i] + bnh));
                    const float hv = fmaf(z_, hp[i] - n_, n_);
                    bb[i] = f2bfbits(hv);
                }
                const unsigned lo  = bb[0] | (bb[1] << 16);
                const unsigned hi  = bb[2] | (bb[3] << 16);
                const unsigned olo = (unsigned)__shfl_xor((int)lo, 1);
                const unsigned ohi = (unsigned)__shfl_xor((int)hi, 1);
                unsigned w0, w1;
                if (odd) {   // rows rbase+2, rbase+3
                    w0 = (ohi & 0xffffu) | (hi << 16);
                    w1 = (ohi >> 16)     | (hi & 0xffff0000u);
                } else {     // rows rbase+0, rbase+1
                    w0 = (lo & 0xffffu)  | (olo << 16);
                    w1 = (lo >> 16)      | (olo & 0xffff0000u);
                }
                *(unsigned*)((char*)hs + hsoff(rowA,     colb)) = w0;
                *(unsigned*)((char*)hs + hsoff(rowA + 1, colb)) = w1;
            }
        }
        // ---- unit end: reload hf from hs (own rows -> no barrier needed) ----
        if (u < UNITS - 1) {
#pragma unroll
            for (int mt = 0; mt < 2; ++mt)
#pragma unroll
                for (int kc = 0; kc < 8; ++kc)
                    hf[mt][kc] = *(const bf16x8*)((const char*)hs +
                        hsoff(wave * 32 + mt * 16 + l15, kc * 32 + quad * 8));
        }
    }

    // ---- coalesced f32 flush of the final h (cross-wave reads) ----
    __syncthreads();
    {
        const int c8 = (tid & 31) * 8;
        const int r0 = tid >> 5;
#pragma unroll
        for (int i = 0; i < 16; ++i) {
            const int r = r0 + i * 16;
            const bf16x8 v = *(const bf16x8*)((const char*)hs + hsoff(r, c8));
            float4 a, b;
            a.x = (float)v[0]; a.y = (float)v[1]; a.z = (float)v[2]; a.w = (float)v[3];
            b.x = (float)v[4]; b.y = (float)v[5]; b.z = (float)v[6]; b.w = (float)v[7];
            float* o = out + (size_t)(m0 + r) * DIM + c8;
            *(float4*)o       = a;
            *(float4*)(o + 4) = b;
        }
    }
}

// ---------------------------------------------------------------------------
extern "C" void kernel_launch(void* const* d_in, const int* in_sizes, int n_in,
                              void* d_out, int out_size, void* d_ws, size_t ws_size,
                              hipStream_t stream) {
    const float* x   = (const float*)d_in[0];
    const float* Wih = (const float*)d_in[1];   // [8,768,256] f32
    const float* Whh = (const float*)d_in[2];   // [8,768,256] f32
    const float* bih = (const float*)d_in[3];   // [8,768] f32
    const float* bhh = (const float*)d_in[4];   // [8,768] f32
    const float* h0  = (const float*)d_in[5];   // [256] f32
    float* out = (float*)d_out;                 // [B,256] f32

    // ws layout: Wihbf[WN] | Whhbf[WN] (bf16) | bcomb[8*1024] (f32)  ~6.3 MB
    bf16* Wihbf  = (bf16*)d_ws;
    bf16* Whhbf  = Wihbf + WN;
    float* bcomb = (float*)(Whhbf + WN);

    {
        const size_t total = 2 * WN / 4 + (size_t)UNITS * 1024;   // 794,624
        const int cblocks = (int)((total + 255) / 256);
        hipLaunchKernelGGL(convert_kernel, dim3(cblocks), dim3(256), 0, stream,
                           Wih, Whh, bih, bhh, Wihbf, Whhbf, bcomb);
    }
    hipLaunchKernelGGL(gru_fused_kernel, dim3(BATCH / BM), dim3(512), 0, stream,
                       x, h0, Wihbf, Whhbf, bcomb, out);
}

// Round 3
// 701.775 us; speedup vs baseline: 1.5182x; 1.0102x over previous
//
#include <hip/hip_runtime.h>
#include <hip/hip_bf16.h>

typedef __bf16 bf16;
typedef __bf16 bf16x4 __attribute__((ext_vector_type(4)));
typedef __bf16 bf16x8 __attribute__((ext_vector_type(8)));
typedef float f32x4 __attribute__((ext_vector_type(4)));

#define GLD16(gp, sp) __builtin_amdgcn_global_load_lds( \
    (const __attribute__((address_space(1))) void*)(gp), \
    (__attribute__((address_space(3))) void*)(sp), 16, 0, 0)

#define FENCE() asm volatile("" ::: "memory")
#define BARRIER() do { FENCE(); __builtin_amdgcn_s_barrier(); FENCE(); } while (0)

constexpr int UNITS = 8;
constexpr int BATCH = 65536;
constexpr int DIM   = 256;          // I == H == 256
constexpr int BM    = 128;          // rows per block (2 blocks/CU)
constexpr int BN    = 16;           // j-tile columns
constexpr int BK    = 32;           // K per staged buffer (1 MFMA k-step)
constexpr int KC    = DIM / BK;     // 8
constexpr int JT    = DIM / BN;     // 16 j-tiles
constexpr int STEPS_PER_UNIT = JT * KC;             // 128
constexpr int TOT_STEPS = UNITS * STEPS_PER_UNIT;   // 1024
constexpr int WTILE = 3 * BN * BK;  // 1536 bf16 elems = 3 KB (wi or wh)
constexpr size_t WN = (size_t)UNITS * 3 * DIM * DIM;  // 1,572,864 per weight tensor

__device__ __forceinline__ float sigmoidf_fast(float x) {
    return 1.0f / (1.0f + __expf(-x));
}
__device__ __forceinline__ float tanhf_fast(float x) {
    float y = fminf(fmaxf(x, -15.0f), 15.0f);
    float e = __expf(-2.0f * y);
    return (1.0f - e) / (1.0f + e);
}
// byte offset into the swizzled h tile (512B rows): XOR row bits into the
// 16B-slot bits; without it every 16-lane column read is a 16-way conflict.
__device__ __forceinline__ unsigned hsoff(int row, int col) {
    return (unsigned)((row * DIM + col) * 2) ^ (unsigned)((row & 7) << 4);
}
__device__ __forceinline__ float bfbits2f(unsigned b) {
    return __builtin_bit_cast(float, b << 16);
}
__device__ __forceinline__ unsigned f2bfbits(float f) {
    return (unsigned)__builtin_bit_cast(unsigned short, (bf16)f);
}

// ---------------------------------------------------------------------------
// f32 -> bf16 weights, plus combined gate biases:
// bcomb[u][0..256)=bih_r+bhh_r, [256..512)=bih_z+bhh_z, [512..768)=bih_n, [768..1024)=bhh_n
__global__ void convert_kernel(const float* __restrict__ Wih,
                               const float* __restrict__ Whh,
                               const float* __restrict__ bih,
                               const float* __restrict__ bhh,
                               bf16* __restrict__ Wihbf,
                               bf16* __restrict__ Whhbf,
                               float* __restrict__ bcomb)
{
    const size_t W4 = 2 * WN / 4;   // 786432 float4 conversions
    size_t i = (size_t)blockIdx.x * blockDim.x + threadIdx.x;
    if (i < W4) {
        size_t e = i * 4;
        const float* src = (e < WN) ? Wih : Whh;
        bf16* dst        = (e < WN) ? Wihbf : Whhbf;
        size_t off       = (e < WN) ? e : e - WN;
        const float4 v = *(const float4*)(src + off);
        bf16x4 o;
        o[0] = (bf16)v.x; o[1] = (bf16)v.y; o[2] = (bf16)v.z; o[3] = (bf16)v.w;
        *(bf16x4*)(dst + off) = o;
    } else {
        size_t j = i - W4;          // 0..8191
        if (j < (size_t)UNITS * 1024) {
            int u = (int)(j >> 10), t = (int)(j & 1023);
            const float* bi = bih + u * 768;
            const float* bh = bhh + u * 768;
            float v;
            if (t < 512)      v = bi[t] + bh[t];   // r, z merged biases
            else if (t < 768) v = bi[t];           // bni
            else              v = bh[t - 256];     // bnh
            bcomb[u * 1024 + t] = v;
        }
    }
}

// ---------------------------------------------------------------------------
// Stage the (u,jt,kc) weight buffer: wi = 48 rows (3 gates x 16 j) x 32 k,
// wh same -> 6 x 1KB chunks (16 rows x 64B; chunk c == gate for each tensor).
// 64B rows: conflict-free key is slot = quad ^ ((l15 ^ (l15>>2)) & 3); the
// global source k-chunk is pre-swizzled so the LINEAR global_load_lds
// destination yields the swizzled layout (both-sides-or-neither rule).
__device__ __forceinline__ void stage_w(const bf16* __restrict__ Wihbf,
                                        const bf16* __restrict__ Whhbf,
                                        bf16* wb, int sg, int wave, int lane)
{
    const int u  = sg >> 7;
    const int jt = (sg >> 3) & 15;
    const int kc = sg & 7;
    const int k0 = kc * BK;
    const bf16* Wi = Wihbf + (size_t)u * (3 * DIM * DIM);
    const bf16* Wh = Whhbf + (size_t)u * (3 * DIM * DIM);
    const int rr   = lane >> 2;                               // row-in-chunk 0..15
    const int scol = ((lane & 3) ^ ((rr ^ (rr >> 2)) & 3)) << 3;  // pre-swizzled k
    {   // chunks 0..3: wave w -> chunk w (0-2 = wi gate w, 3 = wh gate 0)
        const int c = wave;
        const bf16* W = (c < 3) ? Wi : Wh;
        const int g  = (c < 3) ? c : 0;
        bf16* d = wb + ((c < 3) ? 0 : WTILE) + g * 512;
        const int grow = g * DIM + jt * BN + rr;
        GLD16(W + (size_t)grow * DIM + k0 + scol, d);
    }
    if (wave < 2) {   // chunks 4..5 -> wh gates 1,2
        const int g = wave + 1;
        const int grow = g * DIM + jt * BN + rr;
        GLD16(Wh + (size_t)grow * DIM + k0 + scol, wb + WTILE + g * 512);
    }
}

// ---------------------------------------------------------------------------
// Fused 8-unit GRU chain. One block = 128 batch rows; TWO blocks per CU so
// the barrier cadences of independent blocks de-lockstep: one block's LDS
// read-burst overlaps the other's MFMA burst (the round-2 kernel serialized
// these inside a single 8-wave block).
// x AND h_prev live in VGPR A-fragments (h rows never cross waves); hs (LDS)
// is the C-layout home of h for the epilogue + once-per-unit A-relayout.
__global__ __launch_bounds__(256, 2)
void gru_fused_kernel(const float* __restrict__ xg,     // [B,256] f32
                      const float* __restrict__ h0g,    // [256] f32
                      const bf16* __restrict__ Wihbf,   // [8,768,256] bf16
                      const bf16* __restrict__ Whhbf,   // [8,768,256] bf16
                      const float* __restrict__ bcomb,  // [8,1024] f32
                      float* __restrict__ out)          // [B,256] f32
{
    __shared__ __align__(16) bf16 hs[BM * DIM];       // 64 KB
    __shared__ __align__(16) bf16 wbuf[2][2 * WTILE]; // 12 KB => 76 KB total

    const int tid  = threadIdx.x;
    const int wave = tid >> 6;      // 0..3
    const int lane = tid & 63;
    const int quad = lane >> 4;
    const int l15  = lane & 15;
    const int odd  = l15 & 1;
    const int m0   = blockIdx.x * BM;

    // ---- x m-tile -> persistent A-fragments (f32 load, bf16 convert) ----
    bf16x8 xf[2][8];
#pragma unroll
    for (int mt = 0; mt < 2; ++mt) {
        const int row = m0 + wave * 32 + mt * 16 + l15;
        const float* xr = xg + (size_t)row * DIM + quad * 8;
#pragma unroll
        for (int kc = 0; kc < 8; ++kc) {
            const float4 a = *(const float4*)(xr + kc * 32);
            const float4 b = *(const float4*)(xr + kc * 32 + 4);
            bf16x8 v;
            v[0]=(bf16)a.x; v[1]=(bf16)a.y; v[2]=(bf16)a.z; v[3]=(bf16)a.w;
            v[4]=(bf16)b.x; v[5]=(bf16)b.y; v[6]=(bf16)b.z; v[7]=(bf16)b.w;
            xf[mt][kc] = v;
        }
    }

    // ---- h0 -> hf A-fragments (broadcast: same cols for every row) ----
    bf16x8 hf[2][8];
#pragma unroll
    for (int kc = 0; kc < 8; ++kc) {
        const float4 a = *(const float4*)(h0g + kc * 32 + quad * 8);
        const float4 b = *(const float4*)(h0g + kc * 32 + quad * 8 + 4);
        bf16x8 v;
        v[0]=(bf16)a.x; v[1]=(bf16)a.y; v[2]=(bf16)a.z; v[3]=(bf16)a.w;
        v[4]=(bf16)b.x; v[5]=(bf16)b.y; v[6]=(bf16)b.z; v[7]=(bf16)b.w;
        hf[0][kc] = v;
        hf[1][kc] = v;
    }
    // ---- hs := h0 (own rows; epilogue of unit 0 reads h_prev from here) ----
#pragma unroll
    for (int mt = 0; mt < 2; ++mt)
#pragma unroll
        for (int kc = 0; kc < 8; ++kc)
            *(bf16x8*)((char*)hs + hsoff(wave * 32 + mt * 16 + l15,
                                         kc * 32 + quad * 8)) = hf[mt][kc];

    stage_w(Wihbf, Whhbf, (bf16*)wbuf[0], 0, wave, lane);   // prologue stage

    for (int u = 0; u < UNITS; ++u) {
        const float* bc = bcomb + u * 1024;
        for (int jt = 0; jt < JT; ++jt) {
            // bias loads issued at jt top; latency hidden under the k loop
            const int jc = jt * BN + l15;
            const float br  = bc[jc];
            const float bz  = bc[DIM + jc];
            const float bni = bc[2 * DIM + jc];
            const float bnh = bc[3 * DIM + jc];

            f32x4 acc[4][2];   // [r, z, n_i, n_h][mt]
#pragma unroll
            for (int g = 0; g < 4; ++g)
#pragma unroll
                for (int mt = 0; mt < 2; ++mt)
                    acc[g][mt] = (f32x4){0.f, 0.f, 0.f, 0.f};

            const int sg0 = u * STEPS_PER_UNIT + jt * KC;
#pragma unroll
            for (int kc = 0; kc < KC; ++kc) {
                const int sg = sg0 + kc;
                // drain MY stage chunks (issued one body ago), then rendezvous.
                asm volatile("s_waitcnt vmcnt(0)" ::: "memory");
                BARRIER();
                const bf16* wt = wbuf[sg & 1];
                // issue this step's B-frag reads first (shortest path to MFMA)
                bf16x8 bi[3], bh[3];
                const int slot = (quad ^ ((l15 ^ (l15 >> 2)) & 3)) << 3;
#pragma unroll
                for (int g = 0; g < 3; ++g) {
                    const int off = (g * BN + l15) * BK + slot;
                    bi[g] = *(const bf16x8*)(wt + off);
                    bh[g] = *(const bf16x8*)(wt + WTILE + off);
                }
                // then fire next step's staging (full step of slack to land)
                if (sg + 1 < TOT_STEPS)
                    stage_w(Wihbf, Whhbf, (bf16*)wbuf[(sg + 1) & 1],
                            sg + 1, wave, lane);
                __builtin_amdgcn_s_setprio(1);
#pragma unroll
                for (int mt = 0; mt < 2; ++mt) {
                    acc[0][mt] = __builtin_amdgcn_mfma_f32_16x16x32_bf16(xf[mt][kc], bi[0], acc[0][mt], 0, 0, 0);
                    acc[0][mt] = __builtin_amdgcn_mfma_f32_16x16x32_bf16(hf[mt][kc], bh[0], acc[0][mt], 0, 0, 0);
                    acc[1][mt] = __builtin_amdgcn_mfma_f32_16x16x32_bf16(xf[mt][kc], bi[1], acc[1][mt], 0, 0, 0);
                    acc[1][mt] = __builtin_amdgcn_mfma_f32_16x16x32_bf16(hf[mt][kc], bh[1], acc[1][mt], 0, 0, 0);
                    acc[2][mt] = __builtin_amdgcn_mfma_f32_16x16x32_bf16(xf[mt][kc], bi[2], acc[2][mt], 0, 0, 0);
                    acc[3][mt] = __builtin_amdgcn_mfma_f32_16x16x32_bf16(hf[mt][kc], bh[2], acc[3][mt], 0, 0, 0);
                }
                __builtin_amdgcn_s_setprio(0);
            }

            // ---- epilogue: activations, write h_new through to hs ----
            // hf regs still hold full h_prev, so writing hs per-jt is safe.
            // C/D layout: col = l15, row = quad*4 + i. Even/odd lane pairs
            // exchange halves so hs reads/writes are full-dword ops.
#pragma unroll
            for (int mt = 0; mt < 2; ++mt) {
                const int rbase = wave * 32 + mt * 16 + quad * 4;
                const int rowA  = rbase + 2 * odd;
                const int colb  = jt * BN + (l15 & ~1);
                const unsigned d0 = *(const unsigned*)((const char*)hs + hsoff(rowA,     colb));
                const unsigned d1 = *(const unsigned*)((const char*)hs + hsoff(rowA + 1, colb));
                const unsigned o0 = (unsigned)__shfl_xor((int)d0, 1);
                const unsigned o1 = (unsigned)__shfl_xor((int)d1, 1);
                const unsigned p0 = odd ? o0 : d0;   // row rbase+0 col-pair
                const unsigned p1 = odd ? o1 : d1;   // row rbase+1
                const unsigned p2 = odd ? d0 : o0;   // row rbase+2
                const unsigned p3 = odd ? d1 : o1;   // row rbase+3
                const int sh = odd ? 16 : 0;
                float hp[4];
                hp[0] = bfbits2f((p0 >> sh) & 0xffffu);
                hp[1] = bfbits2f((p1 >> sh) & 0xffffu);
                hp[2] = bfbits2f((p2 >> sh) & 0xffffu);
                hp[3] = bfbits2f((p3 >> sh) & 0xffffu);
                unsigned bb[4];
#pragma unroll
                for (int i = 0; i < 4; ++i) {
                    const float r_ = sigmoidf_fast(acc[0][mt][i] + br);
                    const float z_ = sigmoidf_fast(acc[1][mt][i] + bz);
                    const float n_ = tanhf_fast(acc[2][mt][i] + bni
                                                + r_ * (acc[3][mt][i] + bnh));
                    const float hv = fmaf(z_, hp[i] - n_, n_);
                    bb[i] = f2bfbits(hv);
                }
                const unsigned lo  = bb[0] | (bb[1] << 16);
                const unsigned hi  = bb[2] | (bb[3] << 16);
                const unsigned olo = (unsigned)__shfl_xor((int)lo, 1);
                const unsigned ohi = (unsigned)__shfl_xor((int)hi, 1);
                unsigned w0, w1;
                if (odd) {   // rows rbase+2, rbase+3
                    w0 = (ohi & 0xffffu) | (hi << 16);
                    w1 = (ohi >> 16)     | (hi & 0xffff0000u);
                } else {     // rows rbase+0, rbase+1
                    w0 = (lo & 0xffffu)  | (olo << 16);
                    w1 = (lo >> 16)      | (olo & 0xffff0000u);
                }
                *(unsigned*)((char*)hs + hsoff(rowA,     colb)) = w0;
                *(unsigned*)((char*)hs + hsoff(rowA + 1, colb)) = w1;
            }
        }
        // ---- unit end: reload hf from hs (own rows -> no barrier needed) ----
        if (u < UNITS - 1) {
#pragma unroll
            for (int mt = 0; mt < 2; ++mt)
#pragma unroll
                for (int kc = 0; kc < 8; ++kc)
                    hf[mt][kc] = *(const bf16x8*)((const char*)hs +
                        hsoff(wave * 32 + mt * 16 + l15, kc * 32 + quad * 8));
        }
    }

    // ---- coalesced f32 flush of the final h (cross-wave reads) ----
    __syncthreads();
    {
        const int c8 = (tid & 31) * 8;
        const int r0 = tid >> 5;            // 0..7
#pragma unroll
        for (int i = 0; i < 16; ++i) {
            const int r = r0 + i * 8;       // 0..127
            const bf16x8 v = *(const bf16x8*)((const char*)hs + hsoff(r, c8));
            float4 a, b;
            a.x = (float)v[0]; a.y = (float)v[1]; a.z = (float)v[2]; a.w = (float)v[3];
            b.x = (float)v[4]; b.y = (float)v[5]; b.z = (float)v[6]; b.w = (float)v[7];
            float* o = out + (size_t)(m0 + r) * DIM + c8;
            *(float4*)o       = a;
            *(float4*)(o + 4) = b;
        }
    }
}

// ---------------------------------------------------------------------------
extern "C" void kernel_launch(void* const* d_in, const int* in_sizes, int n_in,
                              void* d_out, int out_size, void* d_ws, size_t ws_size,
                              hipStream_t stream) {
    const float* x   = (const float*)d_in[0];
    const float* Wih = (const float*)d_in[1];   // [8,768,256] f32
    const float* Whh = (const float*)d_in[2];   // [8,768,256] f32
    const float* bih = (const float*)d_in[3];   // [8,768] f32
    const float* bhh = (const float*)d_in[4];   // [8,768] f32
    const float* h0  = (const float*)d_in[5];   // [256] f32
    float* out = (float*)d_out;                 // [B,256] f32

    // ws layout: Wihbf[WN] | Whhbf[WN] (bf16) | bcomb[8*1024] (f32)  ~6.3 MB
    bf16* Wihbf  = (bf16*)d_ws;
    bf16* Whhbf  = Wihbf + WN;
    float* bcomb = (float*)(Whhbf + WN);

    {
        const size_t total = 2 * WN / 4 + (size_t)UNITS * 1024;   // 794,624
        const int cblocks = (int)((total + 255) / 256);
        hipLaunchKernelGGL(convert_kernel, dim3(cblocks), dim3(256), 0, stream,
                           Wih, Whh, bih, bhh, Wihbf, Whhbf, bcomb);
    }
    hipLaunchKernelGGL(gru_fused_kernel, dim3(BATCH / BM), dim3(256), 0, stream,
                       x, h0, Wihbf, Whhbf, bcomb, out);
}

// Round 4
// 700.794 us; speedup vs baseline: 1.5203x; 1.0014x over previous
//
#include <hip/hip_runtime.h>
#include <hip/hip_bf16.h>

typedef __bf16 bf16;
typedef __bf16 bf16x4 __attribute__((ext_vector_type(4)));
typedef __bf16 bf16x8 __attribute__((ext_vector_type(8)));
typedef float f32x4 __attribute__((ext_vector_type(4)));

#define GLD16(gp, sp) __builtin_amdgcn_global_load_lds( \
    (const __attribute__((address_space(1))) void*)(gp), \
    (__attribute__((address_space(3))) void*)(sp), 16, 0, 0)

#define FENCE() asm volatile("" ::: "memory")
#define BARRIER() do { FENCE(); __builtin_amdgcn_s_barrier(); FENCE(); } while (0)

constexpr int UNITS = 8;
constexpr int BATCH = 65536;
constexpr int DIM   = 256;          // I == H == 256
constexpr int BM    = 256;          // rows per block (1 block/CU, 8 waves)
constexpr int BN    = 16;           // j-tile columns
constexpr int BK    = 64;           // K per staged buffer (2 MFMA k-chunks)
constexpr int JT    = DIM / BN;     // 16 j-tiles
constexpr int PAIRS = DIM / BK;     // 4 staged buffers per jt
constexpr int STEPS_PER_UNIT = JT * PAIRS;          // 64
constexpr int TOT_STEPS = UNITS * STEPS_PER_UNIT;   // 512
constexpr int WTILE = 3 * BN * BK;  // 3072 bf16 = 6 KB (wi or wh)
constexpr size_t WN = (size_t)UNITS * 3 * DIM * DIM;  // per weight tensor

__device__ __forceinline__ float sigmoidf_fast(float x) {
    return 1.0f / (1.0f + __expf(-x));
}
__device__ __forceinline__ float tanhf_fast(float x) {
    float y = fminf(fmaxf(x, -15.0f), 15.0f);
    float e = __expf(-2.0f * y);
    return (1.0f - e) / (1.0f + e);
}
// swizzled h tile (512B rows): XOR row bits into the 16B-slot bits
__device__ __forceinline__ unsigned hsoff(int row, int col) {
    return (unsigned)((row * DIM + col) * 2) ^ (unsigned)((row & 7) << 4);
}
__device__ __forceinline__ float bfbits2f(unsigned b) {
    return __builtin_bit_cast(float, b << 16);
}
__device__ __forceinline__ unsigned f2bfbits(float f) {
    return (unsigned)__builtin_bit_cast(unsigned short, (bf16)f);
}

// ---------------------------------------------------------------------------
// f32 -> bf16 weights, plus combined gate biases:
// bcomb[u][0..256)=bih_r+bhh_r, [256..512)=bih_z+bhh_z, [512..768)=bih_n, [768..1024)=bhh_n
__global__ void convert_kernel(const float* __restrict__ Wih,
                               const float* __restrict__ Whh,
                               const float* __restrict__ bih,
                               const float* __restrict__ bhh,
                               bf16* __restrict__ Wihbf,
                               bf16* __restrict__ Whhbf,
                               float* __restrict__ bcomb)
{
    const size_t W4 = 2 * WN / 4;
    size_t i = (size_t)blockIdx.x * blockDim.x + threadIdx.x;
    if (i < W4) {
        size_t e = i * 4;
        const float* src = (e < WN) ? Wih : Whh;
        bf16* dst        = (e < WN) ? Wihbf : Whhbf;
        size_t off       = (e < WN) ? e : e - WN;
        const float4 v = *(const float4*)(src + off);
        bf16x4 o;
        o[0] = (bf16)v.x; o[1] = (bf16)v.y; o[2] = (bf16)v.z; o[3] = (bf16)v.w;
        *(bf16x4*)(dst + off) = o;
    } else {
        size_t j = i - W4;
        if (j < (size_t)UNITS * 1024) {
            int u = (int)(j >> 10), t = (int)(j & 1023);
            const float* bi = bih + u * 768;
            const float* bh = bhh + u * 768;
            float v;
            if (t < 512)      v = bi[t] + bh[t];
            else if (t < 768) v = bi[t];
            else              v = bh[t - 256];
            bcomb[u * 1024 + t] = v;
        }
    }
}

// ---------------------------------------------------------------------------
// Stage the (u,jt,pair) weight buffer: wi = 48 rows (3 gates x 16 j) x 64 k,
// wh same -> 12 x 1KB chunks (8 rows x 128B each).  R2-verified geometry:
// 128B rows, conflict-free read key (l15&7); global source k pre-swizzled so
// the linear global_load_lds destination yields the swizzled layout.
__device__ __forceinline__ void stage_w(const bf16* __restrict__ Wihbf,
                                        const bf16* __restrict__ Whhbf,
                                        bf16* wb, int sg, int wave, int lane)
{
    const int u    = sg >> 6;
    const int jt   = (sg >> 2) & 15;
    const int pair = sg & 3;
    const int k0   = pair * 64;
    const bf16* Wi = Wihbf + (size_t)u * (3 * DIM * DIM);
    const bf16* Wh = Whhbf + (size_t)u * (3 * DIM * DIM);
    const int rr   = lane >> 3;                 // row-in-chunk 0..7
    const int scol = ((lane & 7) ^ rr) << 3;    // pre-swizzled k elems
    {   // chunk c = wave: c<6 -> wi chunk c, else wh chunk c-6
        const int c  = wave;
        const bf16* W = (c < 6) ? Wi : Wh;
        const int cc = (c < 6) ? c : c - 6;
        bf16* d = wb + ((c < 6) ? 0 : WTILE) + cc * 512;
        const int r = cc * 8 + rr;              // tile row 0..47
        const int grow = (r >> 4) * DIM + jt * BN + (r & 15);
        GLD16(W + (size_t)grow * DIM + k0 + scol, d);
    }
    if (wave < 4) {   // chunks 8..11 -> wh chunks 2..5
        const int cc = wave + 2;
        const int r = cc * 8 + rr;
        const int grow = (r >> 4) * DIM + jt * BN + (r & 15);
        GLD16(Wh + (size_t)grow * DIM + k0 + scol, wb + WTILE + cc * 512);
    }
}

// read one half-buffer (kc2 = 0/1) of B-fragments
#define READ6(BI, BH, WT, KC2) do {                                          \
    _Pragma("unroll")                                                        \
    for (int g_ = 0; g_ < 3; ++g_) {                                         \
        const int off_ = (g_ * BN + l15) * BK                                \
                       + ((((KC2) * 4 + quad) ^ (l15 & 7)) << 3);            \
        BI[g_] = *(const bf16x8*)((WT) + off_);                              \
        BH[g_] = *(const bf16x8*)((WT) + WTILE + off_);                      \
    }                                                                        \
} while (0)

// 12 MFMAs of one k-chunk (kcg compile-time)
#define MFMA12(BI, BH, KCG) do {                                             \
    __builtin_amdgcn_s_setprio(1);                                           \
    _Pragma("unroll")                                                        \
    for (int mt_ = 0; mt_ < 2; ++mt_) {                                      \
        acc[0][mt_] = __builtin_amdgcn_mfma_f32_16x16x32_bf16(xf[mt_][KCG], BI[0], acc[0][mt_], 0, 0, 0); \
        acc[0][mt_] = __builtin_amdgcn_mfma_f32_16x16x32_bf16(hf[mt_][KCG], BH[0], acc[0][mt_], 0, 0, 0); \
        acc[1][mt_] = __builtin_amdgcn_mfma_f32_16x16x32_bf16(xf[mt_][KCG], BI[1], acc[1][mt_], 0, 0, 0); \
        acc[1][mt_] = __builtin_amdgcn_mfma_f32_16x16x32_bf16(hf[mt_][KCG], BH[1], acc[1][mt_], 0, 0, 0); \
        acc[2][mt_] = __builtin_amdgcn_mfma_f32_16x16x32_bf16(xf[mt_][KCG], BI[2], acc[2][mt_], 0, 0, 0); \
        acc[3][mt_] = __builtin_amdgcn_mfma_f32_16x16x32_bf16(hf[mt_][KCG], BH[2], acc[3][mt_], 0, 0, 0); \
    }                                                                        \
    __builtin_amdgcn_s_setprio(0);                                           \
} while (0)

// ---------------------------------------------------------------------------
// Fused 8-unit GRU chain, 1 block/CU, 8 waves. Software-pipelined K-loop:
// each pair's kc2=1 MFMAs execute at the TOP of the next pair, BEFORE the
// vmcnt/barrier, so MFMA overlaps the CU-wide LDS read burst + barrier skew.
__global__ __launch_bounds__(512, 2)
void gru_fused_kernel(const float* __restrict__ xg,     // [B,256] f32
                      const float* __restrict__ h0g,    // [256] f32
                      const bf16* __restrict__ Wihbf,   // [8,768,256] bf16
                      const bf16* __restrict__ Whhbf,   // [8,768,256] bf16
                      const float* __restrict__ bcomb,  // [8,1024] f32
                      float* __restrict__ out)          // [B,256] f32
{
    __shared__ __align__(16) bf16 hs[BM * DIM];       // 128 KB
    __shared__ __align__(16) bf16 wbuf[2][2 * WTILE]; // 24 KB  => 152 KB

    const int tid  = threadIdx.x;
    const int wave = tid >> 6;      // 0..7
    const int lane = tid & 63;
    const int quad = lane >> 4;
    const int l15  = lane & 15;
    const int odd  = l15 & 1;
    const int m0   = blockIdx.x * BM;

    // ---- x m-tile -> persistent A-fragments (f32 load, bf16 convert) ----
    bf16x8 xf[2][8];
#pragma unroll
    for (int mt = 0; mt < 2; ++mt) {
        const int row = m0 + wave * 32 + mt * 16 + l15;
        const float* xr = xg + (size_t)row * DIM + quad * 8;
#pragma unroll
        for (int kc = 0; kc < 8; ++kc) {
            const float4 a = *(const float4*)(xr + kc * 32);
            const float4 b = *(const float4*)(xr + kc * 32 + 4);
            bf16x8 v;
            v[0]=(bf16)a.x; v[1]=(bf16)a.y; v[2]=(bf16)a.z; v[3]=(bf16)a.w;
            v[4]=(bf16)b.x; v[5]=(bf16)b.y; v[6]=(bf16)b.z; v[7]=(bf16)b.w;
            xf[mt][kc] = v;
        }
    }

    // ---- h0 -> hf A-fragments (broadcast) + hs init (own rows) ----
    bf16x8 hf[2][8];
#pragma unroll
    for (int kc = 0; kc < 8; ++kc) {
        const float4 a = *(const float4*)(h0g + kc * 32 + quad * 8);
        const float4 b = *(const float4*)(h0g + kc * 32 + quad * 8 + 4);
        bf16x8 v;
        v[0]=(bf16)a.x; v[1]=(bf16)a.y; v[2]=(bf16)a.z; v[3]=(bf16)a.w;
        v[4]=(bf16)b.x; v[5]=(bf16)b.y; v[6]=(bf16)b.z; v[7]=(bf16)b.w;
        hf[0][kc] = v;
        hf[1][kc] = v;
    }
#pragma unroll
    for (int mt = 0; mt < 2; ++mt)
#pragma unroll
        for (int kc = 0; kc < 8; ++kc)
            *(bf16x8*)((char*)hs + hsoff(wave * 32 + mt * 16 + l15,
                                         kc * 32 + quad * 8)) = hf[mt][kc];

    // ---- bias regs for (u=0, jt=0) + prologue stage ----
    float bc0, bc1, bc2, bc3;             // r, z, n_i, n_h biases (col jt*16+l15)
    float bn0 = 0.f, bn1 = 0.f, bn2 = 0.f, bn3 = 0.f;
    {
        const float* bp = bcomb + l15;
        bc0 = bp[0]; bc1 = bp[256]; bc2 = bp[512]; bc3 = bp[768];
    }
    stage_w(Wihbf, Whhbf, (bf16*)wbuf[0], 0, wave, lane);

    for (int u = 0; u < UNITS; ++u) {
        for (int jt = 0; jt < JT; ++jt) {
            // biases folded into accumulator init
            f32x4 acc[4][2];
#pragma unroll
            for (int mt = 0; mt < 2; ++mt) {
                acc[0][mt] = (f32x4){bc0, bc0, bc0, bc0};
                acc[1][mt] = (f32x4){bc1, bc1, bc1, bc1};
                acc[2][mt] = (f32x4){bc2, bc2, bc2, bc2};
                acc[3][mt] = (f32x4){bc3, bc3, bc3, bc3};
            }
            bf16x8 biA[3], bhA[3], biB[3], bhB[3];
            const int sgb = u * STEPS_PER_UNIT + jt * PAIRS;

#pragma unroll
            for (int pair = 0; pair < PAIRS; ++pair) {
                // finish the PREVIOUS pair's second k-chunk before the
                // barrier: overlaps this MFMA burst with other waves' reads
                // and with our own stage/barrier wait.
                if (pair == 1) MFMA12(biB, bhB, 1);
                if (pair == 2) MFMA12(biB, bhB, 3);
                if (pair == 3) MFMA12(biB, bhB, 5);

                asm volatile("s_waitcnt vmcnt(0)" ::: "memory");
                BARRIER();   // buf[pair&1] globally ready
                const bf16* wt = wbuf[pair & 1];
                READ6(biA, bhA, wt, 0);
                if (sgb + pair + 1 < TOT_STEPS)
                    stage_w(Wihbf, Whhbf, (bf16*)wbuf[(pair + 1) & 1],
                            sgb + pair + 1, wave, lane);
                if (pair == 1) {   // prefetch next jt's biases (used in ~3 pairs)
                    const int njt = (jt + 1) & 15;
                    const int nu  = (jt == 15) ? u + 1 : u;
                    if (nu < UNITS) {
                        const float* bp = bcomb + nu * 1024 + njt * BN + l15;
                        bn0 = bp[0]; bn1 = bp[256]; bn2 = bp[512]; bn3 = bp[768];
                    }
                }
                if (pair == 0) MFMA12(biA, bhA, 0);
                if (pair == 1) MFMA12(biA, bhA, 2);
                if (pair == 2) MFMA12(biA, bhA, 4);
                if (pair == 3) MFMA12(biA, bhA, 6);
                READ6(biB, bhB, wt, 1);
            }
            MFMA12(biB, bhB, 7);   // pipeline flush for this jt

            // ---- epilogue: activations, write h_new through to hs ----
            // biases already inside acc. C/D layout: col = l15, row = quad*4+i.
#pragma unroll
            for (int mt = 0; mt < 2; ++mt) {
                const int rbase = wave * 32 + mt * 16 + quad * 4;
                const int rowA  = rbase + 2 * odd;
                const int colb  = jt * BN + (l15 & ~1);
                const unsigned d0 = *(const unsigned*)((const char*)hs + hsoff(rowA,     colb));
                const unsigned d1 = *(const unsigned*)((const char*)hs + hsoff(rowA + 1, colb));
                const unsigned o0 = (unsigned)__shfl_xor((int)d0, 1);
                const unsigned o1 = (unsigned)__shfl_xor((int)d1, 1);
                const unsigned p0 = odd ? o0 : d0;
                const unsigned p1 = odd ? o1 : d1;
                const unsigned p2 = odd ? d0 : o0;
                const unsigned p3 = odd ? d1 : o1;
                const int sh = odd ? 16 : 0;
                float hp[4];
                hp[0] = bfbits2f((p0 >> sh) & 0xffffu);
                hp[1] = bfbits2f((p1 >> sh) & 0xffffu);
                hp[2] = bfbits2f((p2 >> sh) & 0xffffu);
                hp[3] = bfbits2f((p3 >> sh) & 0xffffu);
                unsigned bb[4];
#pragma unroll
                for (int i = 0; i < 4; ++i) {
                    const float r_ = sigmoidf_fast(acc[0][mt][i]);
                    const float z_ = sigmoidf_fast(acc[1][mt][i]);
                    const float n_ = tanhf_fast(acc[2][mt][i] + r_ * acc[3][mt][i]);
                    const float hv = fmaf(z_, hp[i] - n_, n_);
                    bb[i] = f2bfbits(hv);
                }
                const unsigned lo  = bb[0] | (bb[1] << 16);
                const unsigned hi  = bb[2] | (bb[3] << 16);
                const unsigned olo = (unsigned)__shfl_xor((int)lo, 1);
                const unsigned ohi = (unsigned)__shfl_xor((int)hi, 1);
                unsigned w0, w1;
                if (odd) {
                    w0 = (ohi & 0xffffu) | (hi << 16);
                    w1 = (ohi >> 16)     | (hi & 0xffff0000u);
                } else {
                    w0 = (lo & 0xffffu)  | (olo << 16);
                    w1 = (lo >> 16)      | (olo & 0xffff0000u);
                }
                *(unsigned*)((char*)hs + hsoff(rowA,     colb)) = w0;
                *(unsigned*)((char*)hs + hsoff(rowA + 1, colb)) = w1;
            }
            bc0 = bn0; bc1 = bn1; bc2 = bn2; bc3 = bn3;
        }
        // ---- unit end: reload hf from hs (own rows -> no barrier needed) ----
        if (u < UNITS - 1) {
#pragma unroll
            for (int mt = 0; mt < 2; ++mt)
#pragma unroll
                for (int kc = 0; kc < 8; ++kc)
                    hf[mt][kc] = *(const bf16x8*)((const char*)hs +
                        hsoff(wave * 32 + mt * 16 + l15, kc * 32 + quad * 8));
        }
    }

    // ---- coalesced f32 flush of the final h (cross-wave reads) ----
    __syncthreads();
    {
        const int c8 = (tid & 31) * 8;
        const int r0 = tid >> 5;            // 0..15
#pragma unroll
        for (int i = 0; i < 16; ++i) {
            const int r = r0 + i * 16;      // 0..255
            const bf16x8 v = *(const bf16x8*)((const char*)hs + hsoff(r, c8));
            float4 a, b;
            a.x = (float)v[0]; a.y = (float)v[1]; a.z = (float)v[2]; a.w = (float)v[3];
            b.x = (float)v[4]; b.y = (float)v[5]; b.z = (float)v[6]; b.w = (float)v[7];
            float* o = out + (size_t)(m0 + r) * DIM + c8;
            *(float4*)o       = a;
            *(float4*)(o + 4) = b;
        }
    }
}

// ---------------------------------------------------------------------------
extern "C" void kernel_launch(void* const* d_in, const int* in_sizes, int n_in,
                              void* d_out, int out_size, void* d_ws, size_t ws_size,
                              hipStream_t stream) {
    const float* x   = (const float*)d_in[0];
    const float* Wih = (const float*)d_in[1];   // [8,768,256] f32
    const float* Whh = (const float*)d_in[2];   // [8,768,256] f32
    const float* bih = (const float*)d_in[3];   // [8,768] f32
    const float* bhh = (const float*)d_in[4];   // [8,768] f32
    const float* h0  = (const float*)d_in[5];   // [256] f32
    float* out = (float*)d_out;                 // [B,256] f32

    // ws layout: Wihbf[WN] | Whhbf[WN] (bf16) | bcomb[8*1024] (f32)
    bf16* Wihbf  = (bf16*)d_ws;
    bf16* Whhbf  = Wihbf + WN;
    float* bcomb = (float*)(Whhbf + WN);

    {
        const size_t total = 2 * WN / 4 + (size_t)UNITS * 1024;
        const int cblocks = (int)((total + 255) / 256);
        hipLaunchKernelGGL(convert_kernel, dim3(cblocks), dim3(256), 0, stream,
                           Wih, Whh, bih, bhh, Wihbf, Whhbf, bcomb);
    }
    hipLaunchKernelGGL(gru_fused_kernel, dim3(BATCH / BM), dim3(512), 0, stream,
                       x, h0, Wihbf, Whhbf, bcomb, out);
}